// Round 1
// baseline (226.754 us; speedup 1.0000x reference)
//
#include <hip/hip_runtime.h>

#define CC 14        // num labels
#define MAXT 13      // max trials
#define RPB 16       // rows per block (16 threads per row, 256 threads)
#define RAMP_CAP 1.8f

__global__ __launch_bounds__(256) void rwl_kernel(
    const float* __restrict__ inp, const int* __restrict__ target,
    const float* __restrict__ S, const float* __restrict__ rand_u,
    float* __restrict__ out, int B)
{
    __shared__ float s_inp[RPB][16];          // padded to 16
    __shared__ int   s_tgt[RPB][16];
    __shared__ unsigned char s_negpos[RPB][CC];
    __shared__ int   s_nn[RPB];
    __shared__ float s_si[RPB];
    __shared__ float s_L[CC];
    __shared__ float s_red[4];

    const int tid  = threadIdx.x;
    const int base = blockIdx.x * RPB;

    // Phase A: coalesced load of 16 rows of inp/target into LDS
    if (tid < RPB * CC) {
        int r = tid / CC, c = tid % CC;
        if (base + r < B) {
            size_t g = (size_t)(base + r) * CC + c;
            s_inp[r][c] = inp[g];
            s_tgt[r][c] = target[g];
        }
    }
    if (tid == 0) {
        // harmonic weights: L[i] = sum_{r=1..i+1} 1/r, float32 cumsum order
        float acc = 0.f;
        for (int r = 1; r <= CC; ++r) { acc += 1.0f / (float)r; s_L[r - 1] = acc; }
    }
    __syncthreads();

    const int r   = tid >> 4;   // row within block: 0..15
    const int j   = tid & 15;   // label: 0..15 (14,15 idle)
    const int row = base + r;

    // Phase B: per-row negative-position list (stable order) + s_i
    if (j == 0 && row < B) {
        int n = 0;
        for (int c = 0; c < CC; ++c)
            if (s_tgt[r][c] == 0) s_negpos[r][n++] = (unsigned char)c;
        s_nn[r] = n;
        s_si[r] = (row <= 14) ? 1.0f : S[row - 14];   // idx <= L_PARAM -> 1
    }
    __syncthreads();

    // Phase C: per-(row,label) work
    float my = 0.f;
    if (j < CC && row < B) {
        const int   tgt = s_tgt[r][j];
        const float x   = s_inp[r][j];
        // kappa term: clip(1 - t*x, 0, 1.8); t==0 -> 1
        const float rk = (tgt == 1) ? fminf(fmaxf(1.0f - x, 0.f), RAMP_CAP) : 1.0f;
        float contrib = 2.0f * rk;   // KAPPA = 2
        const int nn = s_nn[r];
        if (tgt == 1 && nn > 0) {
            // neg_sum: sum over negative k of clip(x - inp[k], 0, 1.8)
            float nsum = 0.f;
            #pragma unroll
            for (int c = 0; c < CC; ++c) {
                if (s_tgt[r][c] == 0) {
                    float d = x - s_inp[r][c];
                    nsum += fminf(fmaxf(d, 0.f), RAMP_CAP);
                }
            }
            // sequential trials with early exit (reads only needed rand_u)
            const float* ru = rand_u + ((size_t)row * CC + j) * MAXT;
            const float fnn = (float)nn;
            int nt = MAXT;
            for (int t = 0; t < MAXT; ++t) {
                float u  = ru[t];
                int   ti = (int)(u * fnn);                 // trunc, matches astype(int32)
                ti = ti < 0 ? 0 : (ti > nn - 1 ? nn - 1 : ti);
                // margin = (1 - x) + inp[k], same association as reference
                float m = 1.0f - x + s_inp[r][s_negpos[r][ti]];
                if (m >= 0.f) { nt = t + 1; break; }
            }
            contrib += s_L[MAXT / nt] * nsum;   // r_j = 13 // num_trials
        }
        my = s_si[r] * contrib;
    }

    // block reduction: wave shuffle then LDS across 4 waves
    #pragma unroll
    for (int off = 32; off > 0; off >>= 1)
        my += __shfl_down(my, off, 64);
    const int wave = tid >> 6;
    if ((tid & 63) == 0) s_red[wave] = my;
    __syncthreads();
    if (tid == 0) {
        float t = s_red[0] + s_red[1] + s_red[2] + s_red[3];
        atomicAdd(out, t);
    }
}

extern "C" void kernel_launch(void* const* d_in, const int* in_sizes, int n_in,
                              void* d_out, int out_size, void* d_ws, size_t ws_size,
                              hipStream_t stream) {
    const float* inp    = (const float*)d_in[0];
    const int*   target = (const int*)d_in[1];
    const float* S      = (const float*)d_in[2];
    const float* ru     = (const float*)d_in[3];
    float*       out    = (float*)d_out;
    const int B = in_sizes[2];   // S has B elements

    // d_out is poisoned and not re-zeroed between replays: zero it each call
    hipMemsetAsync(out, 0, sizeof(float), stream);

    const int blocks = (B + RPB - 1) / RPB;
    rwl_kernel<<<blocks, 256, 0, stream>>>(inp, target, S, ru, out, B);
}

// Round 2
// 73.975 us; speedup vs baseline: 3.0653x; 3.0653x over previous
//
#include <hip/hip_runtime.h>

#define CC   14      // num labels
#define MAXT 13      // max trials
#define TPB  256     // one row per thread
#define RAMP_CAP 1.8f

__global__ __launch_bounds__(TPB) void rwl_kernel(
    const float* __restrict__ inp, const int* __restrict__ target,
    const float* __restrict__ S, const float* __restrict__ rand_u,
    float* __restrict__ out, int B)
{
    // transposed: s_x[k][tid] — each thread only touches its own column,
    // bank = tid%32 -> conflict-free, and no barrier needed.
    __shared__ float s_x[CC][TPB];
    __shared__ float s_red[4];

    const int tid = threadIdx.x;
    const int row = blockIdx.x * TPB + tid;

    float total = 0.f;
    if (row < B) {
        const float* xrow = inp + (size_t)row * CC;
        const int*   trow = target + (size_t)row * CC;

        // row of inp -> registers (static idx) + LDS column (runtime idx)
        float x[CC];
        #pragma unroll
        for (int k = 0; k < CC; ++k) {
            x[k] = xrow[k];
            s_x[k][tid] = x[k];
        }

        // masks, packed negative-position nibbles, kappa sum
        unsigned posmask = 0;
        unsigned long long np64 = 0ull;   // nibble ti -> label index of ti-th negative
        int nn = 0;
        float kap = 0.f;
        #pragma unroll
        for (int k = 0; k < CC; ++k) {
            int tv = trow[k];
            if (tv == 0) {
                np64 |= (unsigned long long)k << (4 * nn);
                ++nn;
                kap += 1.0f;                         // clip(1-0*x,0,1.8)=1
            } else {
                posmask |= (1u << k);
                kap += fminf(fmaxf(1.0f - x[k], 0.f), RAMP_CAP);
            }
        }

        unsigned pend = (nn > 0) ? posmask : 0u;

        // neg_sum per label: sum over negatives k of clip(x_j - x_k, 0, 1.8)
        float nsum[CC];
        #pragma unroll
        for (int j = 0; j < CC; ++j) {
            float s = 0.f;
            #pragma unroll
            for (int k = 0; k < CC; ++k) {
                float c = fminf(fmaxf(x[j] - x[k], 0.f), RAMP_CAP);
                if (!((posmask >> k) & 1u)) s += c;
            }
            nsum[j] = s;
        }

        // harmonic weights, fp32 chain in reference cumsum order
        float a = 1.0f;
        a += 0.5f;            const float W_1 = a;   // L[1] = H2  (r=1)
        a += (1.0f/3.0f);     const float W_2 = a;   // L[2] = H3  (r=2)
        a += 0.25f;           const float W_3 = a;   // L[3] = H4  (r=3)
        a += 0.2f;            const float W_4 = a;   // L[4] = H5  (r=4)
        a += (1.0f/6.0f);
        a += (1.0f/7.0f);     const float W_6 = a;   // L[6] = H7  (r=6)
        a += 0.125f; a += (1.0f/9.0f); a += 0.1f;
        a += (1.0f/11.0f); a += (1.0f/12.0f); a += (1.0f/13.0f); a += (1.0f/14.0f);
        const float W_13 = a;                        // L[13] = H14 (r=13)

        // pass-structured trial loop: batch independent loads for all pending
        // labels each pass -> ~7-14 loads in flight per thread
        float lw = 0.f;
        const float fnn = (float)nn;
        const float* pu = rand_u + (size_t)row * (CC * MAXT);

        for (int t = 0; t < MAXT && pend; ++t) {
            float uv[CC];
            #pragma unroll
            for (int j = 0; j < CC; ++j)
                if (pend & (1u << j)) uv[j] = pu[j * MAXT + t];

            // weight L[13 // (t+1)] — wave-uniform select
            float wt = W_1;
            if      (t == 0) wt = W_13;
            else if (t == 1) wt = W_6;
            else if (t == 2) wt = W_4;
            else if (t == 3) wt = W_3;
            else if (t == 4 || t == 5) wt = W_2;

            float rs = 0.f;
            unsigned resolved = 0u;
            #pragma unroll
            for (int j = 0; j < CC; ++j) {
                if (pend & (1u << j)) {
                    int ti = (int)(uv[j] * fnn);           // trunc == astype(int32)
                    ti = ti < 0 ? 0 : ti;
                    ti = ti > nn - 1 ? nn - 1 : ti;
                    int kk = (int)((np64 >> (4 * ti)) & 15ull);
                    float m = (1.0f - x[j]) + s_x[kk][tid]; // same assoc as ref
                    if (m >= 0.f) { rs += nsum[j]; resolved |= (1u << j); }
                }
            }
            lw += wt * rs;
            pend &= ~resolved;
        }
        if (pend) {          // never resolved: num_trials = 13 -> r=1 -> L[1]
            float rs = 0.f;
            #pragma unroll
            for (int j = 0; j < CC; ++j)
                if (pend & (1u << j)) rs += nsum[j];
            lw += W_1 * rs;
        }

        const float si = (row <= 14) ? 1.0f : S[row - 14];
        total = si * (lw + 2.0f * kap);
    }

    // block reduction: wave shuffle, then LDS across 4 waves, 1 atomic/block
    #pragma unroll
    for (int off = 32; off > 0; off >>= 1)
        total += __shfl_down(total, off, 64);
    const int wave = tid >> 6;
    if ((tid & 63) == 0) s_red[wave] = total;
    __syncthreads();
    if (tid == 0)
        atomicAdd(out, s_red[0] + s_red[1] + s_red[2] + s_red[3]);
}

extern "C" void kernel_launch(void* const* d_in, const int* in_sizes, int n_in,
                              void* d_out, int out_size, void* d_ws, size_t ws_size,
                              hipStream_t stream) {
    const float* inp    = (const float*)d_in[0];
    const int*   target = (const int*)d_in[1];
    const float* S      = (const float*)d_in[2];
    const float* ru     = (const float*)d_in[3];
    float*       out    = (float*)d_out;
    const int B = in_sizes[2];   // S has B elements

    // d_out is poisoned and not re-zeroed between replays: zero it each call
    hipMemsetAsync(out, 0, sizeof(float), stream);

    const int blocks = (B + TPB - 1) / TPB;
    rwl_kernel<<<blocks, TPB, 0, stream>>>(inp, target, S, ru, out, B);
}